// Round 25
// baseline (2006.171 us; speedup 1.0000x reference)
//
#include <hip/hip_runtime.h>
#include <float.h>

// VectorQuantizer: N=262144 rows of D=64 fp32, K=1024 codebook rows.
// out = [x_quantized (N*D f32) | embed_inds (N, written as f32)]
//
// R25 = R24 (bf16 MFMA filter + exact fp32 rescore — hardware-validated,
// absmax 0.0) with the register spill removed (R24: VGPR=128 cap, +81MB
// scratch WRITE, 17% occupancy):
//   - BM 256->128: each wave owns 2 row-tiles (rmv[2][4], 2 A-frag pairs).
//   - ks loop unroll 16 -> 2: stops B-frag hoisting across iterations.
//   - LDS ~57KB -> 2 blocks/CU.
// Filter: mfma_f32_16x16x32_bf16 (D=64 via 2 chained MFMA). Pass1 per-row
// min (shfl_xor over the 16 D-col lanes) -> threshold min+MARGIN. Pass2
// identical sweep pushes all (row,k) under threshold into per-row LDS slots.
// MARGIN 3e-3 >= 2x deterministic worst-case bf16-RNE score error.
// Rescore: R4-verified bit-exact chain, first-min; cnt>8 -> exact full scan.

typedef __attribute__((ext_vector_type(8))) short short8;
typedef __attribute__((ext_vector_type(4))) float f32x4;

static constexpr int D_DIM = 64;
static constexpr int K_CB  = 1024;
static constexpr int TPB   = 256;          // 4 waves
static constexpr int BM    = 128;          // x rows per block (2 row-tiles/wave)
static constexpr int KTR   = 256;          // cb rows per staged bf16 tile
static constexpr int NKT   = K_CB / KTR;   // 4
static constexpr float MARGIN = 3e-3f;

// bf16 RNE pack of two f32 -> uint (lo = bf16(a), hi = bf16(b))
__device__ __forceinline__ unsigned bf2(float a, float b) {
    unsigned ua = __float_as_uint(a), ub = __float_as_uint(b);
    ua += 0x7FFFu + ((ua >> 16) & 1u);
    ub += 0x7FFFu + ((ub >> 16) & 1u);
    return (ua >> 16) | (ub & 0xFFFF0000u);
}

// numpy pairwise-8 sum of squares of 64 values held as 16 float4s.
#define NP_INIT(c0, c1)                                                     \
    float ax = __fmul_rn(c0.x, c0.x), ay = __fmul_rn(c0.y, c0.y),           \
          az = __fmul_rn(c0.z, c0.z), aw = __fmul_rn(c0.w, c0.w);           \
    float bx = __fmul_rn(c1.x, c1.x), by = __fmul_rn(c1.y, c1.y),           \
          bz = __fmul_rn(c1.z, c1.z), bw = __fmul_rn(c1.w, c1.w);
#define NP_ACC(ce, co)                                                      \
    ax = __fadd_rn(ax, __fmul_rn(ce.x, ce.x));                              \
    ay = __fadd_rn(ay, __fmul_rn(ce.y, ce.y));                              \
    az = __fadd_rn(az, __fmul_rn(ce.z, ce.z));                              \
    aw = __fadd_rn(aw, __fmul_rn(ce.w, ce.w));                              \
    bx = __fadd_rn(bx, __fmul_rn(co.x, co.x));                              \
    by = __fadd_rn(by, __fmul_rn(co.y, co.y));                              \
    bz = __fadd_rn(bz, __fmul_rn(co.z, co.z));                              \
    bw = __fadd_rn(bw, __fmul_rn(co.w, co.w));
#define NP_TREE()                                                           \
    __fadd_rn(__fadd_rn(__fadd_rn(ax, ay), __fadd_rn(az, aw)),              \
              __fadd_rn(__fadd_rn(bx, by), __fadd_rn(bz, bw)))

__device__ __forceinline__ float np_pair_sq16(
        float4 c0, float4 c1, float4 c2, float4 c3,
        float4 c4, float4 c5, float4 c6, float4 c7,
        float4 c8, float4 c9, float4 c10, float4 c11,
        float4 c12, float4 c13, float4 c14, float4 c15) {
    NP_INIT(c0, c1)
    NP_ACC(c2, c3)  NP_ACC(c4, c5)  NP_ACC(c6, c7)
    NP_ACC(c8, c9)  NP_ACC(c10, c11) NP_ACC(c12, c13) NP_ACC(c14, c15)
    return NP_TREE();
}

// Exact score: R4-verified bit-exact chain.
__device__ __forceinline__ float exact_sc(const float* xp, const float* cb,
                                          int k, float xn, float en) {
    const float4* xr = reinterpret_cast<const float4*>(xp);
    const float4* cr = reinterpret_cast<const float4*>(cb + (size_t)k * D_DIM);
    float d = 0.f;
#pragma unroll
    for (int c = 0; c < 16; ++c) {
        const float4 xv = xr[c], q = cr[c];
        d = __fmaf_rn(q.x, xv.x, d);
        d = __fmaf_rn(q.y, xv.y, d);
        d = __fmaf_rn(q.z, xv.z, d);
        d = __fmaf_rn(q.w, xv.w, d);
    }
    return __fmaf_rn(-2.f, d, __fadd_rn(xn, en));
}

__global__ void __launch_bounds__(TPB)
__attribute__((amdgpu_waves_per_eu(2, 2)))
vq_kernel(
        const float* __restrict__ x, const float* __restrict__ cb,
        float* __restrict__ out_q, float* __restrict__ out_idx) {
    __shared__ short xbf[BM * D_DIM];    // 16 KB bf16 x tile (swizzled rows)
    __shared__ short cbf[KTR * D_DIM];   // 32 KB bf16 cb tile (swizzled rows)
    __shared__ float es[K_CB];           // 4 KB
    __shared__ int   slots[BM * 8];      // 4 KB candidate slots
    __shared__ int   cnt[BM];            // 0.5 KB
    __shared__ int   bks[BM];            // 0.5 KB   total ~57 KB -> 2 blocks/CU

    const int tid = threadIdx.x;
    const int l   = tid & 63;
    const int w   = tid >> 6;
    const int lm  = l & 15;      // A-row / B-col / D-col lane component
    const int lg  = l >> 4;      // d-group / D-row-group component
    const size_t brow0 = (size_t)blockIdx.x * BM;
    const float4* cb4 = reinterpret_cast<const float4*>(cb);
    char* xb = reinterpret_cast<char*>(xbf);
    char* cc = reinterpret_cast<char*>(cbf);

    // ---- phase A: e-norms (numpy pairwise order, R4-verified) ----
#pragma unroll
    for (int j = 0; j < K_CB / TPB; ++j) {
        const int k = tid + TPB * j;
        const float4* cr = cb4 + (size_t)k * 16;
        float4 c0 = cr[0],  c1 = cr[1],  c2 = cr[2],  c3 = cr[3],
               c4 = cr[4],  c5 = cr[5],  c6 = cr[6],  c7 = cr[7],
               c8 = cr[8],  c9 = cr[9],  c10 = cr[10], c11 = cr[11],
               c12 = cr[12], c13 = cr[13], c14 = cr[14], c15 = cr[15];
        es[k] = np_pair_sq16(c0, c1, c2, c3, c4, c5, c6, c7,
                             c8, c9, c10, c11, c12, c13, c14, c15);
    }

    // ---- phase B (tid<BM): my row -> xn (fp32, numpy) + bf16 row into xbf ----
    float xn = 0.f;
    if (tid < BM) {
        const float4* ga = reinterpret_cast<const float4*>(x + (brow0 + tid) * D_DIM);
        float4 v0 = ga[0],  v1 = ga[1],  v2 = ga[2],  v3 = ga[3],
               v4 = ga[4],  v5 = ga[5],  v6 = ga[6],  v7 = ga[7],
               v8 = ga[8],  v9 = ga[9],  v10 = ga[10], v11 = ga[11],
               v12 = ga[12], v13 = ga[13], v14 = ga[14], v15 = ga[15];
        xn = np_pair_sq16(v0, v1, v2, v3, v4, v5, v6, v7,
                          v8, v9, v10, v11, v12, v13, v14, v15);
        const int sw = (tid & 7) << 4;
#define XW(c, va, vb) { uint4 wv;                                           \
        wv.x = bf2(va.x, va.y); wv.y = bf2(va.z, va.w);                     \
        wv.z = bf2(vb.x, vb.y); wv.w = bf2(vb.z, vb.w);                     \
        *reinterpret_cast<uint4*>(xb + ((tid * 128 + (c) * 16) ^ sw)) = wv; }
        XW(0, v0,  v1)  XW(1, v2,  v3)  XW(2, v4,  v5)  XW(3, v6,  v7)
        XW(4, v8,  v9)  XW(5, v10, v11) XW(6, v12, v13) XW(7, v14, v15)
#undef XW
        cnt[tid] = 0;
    }

    float rmv[2][4];
#pragma unroll
    for (int i = 0; i < 2; ++i)
#pragma unroll
        for (int r = 0; r < 4; ++r) rmv[i][r] = FLT_MAX;

    // ---- pass 1: MFMA sweep, per-lane running min ----
    for (int kt = 0; kt < NKT; ++kt) {
        __syncthreads();                 // prev readers done (kt=0: es/xbf/cnt ready)
        {   // stage cb tile kt as swizzled bf16
            const float4* src = cb4 + (size_t)kt * KTR * 16;
#pragma unroll
            for (int j = 0; j < KTR * 16 / TPB; ++j) {      // 16
                const int f = tid + TPB * j;
                const int kr = f >> 4, c = f & 15;
                const float4 v = src[f];
                uint2 wv; wv.x = bf2(v.x, v.y); wv.y = bf2(v.z, v.w);
                *reinterpret_cast<uint2*>(cc + ((kr * 128 + c * 8) ^ ((kr & 7) << 4))) = wv;
            }
        }
        __syncthreads();
#pragma unroll
        for (int rtl = 0; rtl < 2; ++rtl) {
            const int rb = w * 32 + rtl * 16 + lm;          // A-frag row
            const int rsw = (rb & 7) << 4;
            const short8 a0 = *reinterpret_cast<const short8*>(
                xb + ((rb * 128 + lg * 16) ^ rsw));
            const short8 a1 = *reinterpret_cast<const short8*>(
                xb + ((rb * 128 + lg * 16 + 64) ^ rsw));
#pragma unroll 2
            for (int ks = 0; ks < 16; ++ks) {
                const int kb = ks * 16 + lm;                // B-frag k-row (tile-local)
                const int ksw = (kb & 7) << 4;
                const short8 b0 = *reinterpret_cast<const short8*>(
                    cc + ((kb * 128 + lg * 16) ^ ksw));
                const short8 b1 = *reinterpret_cast<const short8*>(
                    cc + ((kb * 128 + lg * 16 + 64) ^ ksw));
                f32x4 acc = {0.f, 0.f, 0.f, 0.f};
                acc = __builtin_amdgcn_mfma_f32_16x16x32_bf16(a0, b0, acc, 0, 0, 0);
                acc = __builtin_amdgcn_mfma_f32_16x16x32_bf16(a1, b1, acc, 0, 0, 0);
                const float en = es[kt * KTR + kb];         // my D-col's k
#pragma unroll
                for (int r = 0; r < 4; ++r)
                    rmv[rtl][r] = fminf(rmv[rtl][r], __fmaf_rn(-2.f, acc[r], en));
            }
        }
    }

    // ---- reduce per-row min across the 16 D-col lanes; add margin ----
#pragma unroll
    for (int rtl = 0; rtl < 2; ++rtl)
#pragma unroll
        for (int r = 0; r < 4; ++r) {
            float v = rmv[rtl][r];
            v = fminf(v, __shfl_xor(v, 1));
            v = fminf(v, __shfl_xor(v, 2));
            v = fminf(v, __shfl_xor(v, 4));
            v = fminf(v, __shfl_xor(v, 8));
            rmv[rtl][r] = v + MARGIN;     // now the per-row threshold
        }

    // ---- pass 2: identical sweep; push candidates t < threshold ----
    for (int kt = 0; kt < NKT; ++kt) {
        __syncthreads();
        {
            const float4* src = cb4 + (size_t)kt * KTR * 16;
#pragma unroll
            for (int j = 0; j < KTR * 16 / TPB; ++j) {
                const int f = tid + TPB * j;
                const int kr = f >> 4, c = f & 15;
                const float4 v = src[f];
                uint2 wv; wv.x = bf2(v.x, v.y); wv.y = bf2(v.z, v.w);
                *reinterpret_cast<uint2*>(cc + ((kr * 128 + c * 8) ^ ((kr & 7) << 4))) = wv;
            }
        }
        __syncthreads();
#pragma unroll
        for (int rtl = 0; rtl < 2; ++rtl) {
            const int rb = w * 32 + rtl * 16 + lm;
            const int rsw = (rb & 7) << 4;
            const short8 a0 = *reinterpret_cast<const short8*>(
                xb + ((rb * 128 + lg * 16) ^ rsw));
            const short8 a1 = *reinterpret_cast<const short8*>(
                xb + ((rb * 128 + lg * 16 + 64) ^ rsw));
#pragma unroll 2
            for (int ks = 0; ks < 16; ++ks) {
                const int kb = ks * 16 + lm;
                const int ksw = (kb & 7) << 4;
                const short8 b0 = *reinterpret_cast<const short8*>(
                    cc + ((kb * 128 + lg * 16) ^ ksw));
                const short8 b1 = *reinterpret_cast<const short8*>(
                    cc + ((kb * 128 + lg * 16 + 64) ^ ksw));
                f32x4 acc = {0.f, 0.f, 0.f, 0.f};
                acc = __builtin_amdgcn_mfma_f32_16x16x32_bf16(a0, b0, acc, 0, 0, 0);
                acc = __builtin_amdgcn_mfma_f32_16x16x32_bf16(a1, b1, acc, 0, 0, 0);
                const int k = kt * KTR + kb;
                const float en = es[k];
                const bool c0 = __fmaf_rn(-2.f, acc[0], en) < rmv[rtl][0];
                const bool c1 = __fmaf_rn(-2.f, acc[1], en) < rmv[rtl][1];
                const bool c2 = __fmaf_rn(-2.f, acc[2], en) < rmv[rtl][2];
                const bool c3 = __fmaf_rn(-2.f, acc[3], en) < rmv[rtl][3];
                if (__any((int)(c0 | c1 | c2 | c3))) {
                    const int rowb = w * 32 + rtl * 16 + lg * 4;   // D-row base
                    if (c0) { const int i0 = atomicAdd(&cnt[rowb + 0], 1);
                              if (i0 < 8) slots[(rowb + 0) * 8 + i0] = k; }
                    if (c1) { const int i1 = atomicAdd(&cnt[rowb + 1], 1);
                              if (i1 < 8) slots[(rowb + 1) * 8 + i1] = k; }
                    if (c2) { const int i2 = atomicAdd(&cnt[rowb + 2], 1);
                              if (i2 < 8) slots[(rowb + 2) * 8 + i2] = k; }
                    if (c3) { const int i3 = atomicAdd(&cnt[rowb + 3], 1);
                              if (i3 < 8) slots[(rowb + 3) * 8 + i3] = k; }
                }
            }
        }
    }
    __syncthreads();

    // ---- exact rescore (bit-exact chain, first-min over candidate set) ----
    if (tid < BM) {
        const float* xp = x + (brow0 + tid) * D_DIM;
        float bs = FLT_MAX;
        int bk = 0;
        const int c = cnt[tid];
        if (c > 8) {                     // slot overflow: exact full scan
#pragma unroll 1
            for (int k = 0; k < K_CB; ++k) {
                const float s = exact_sc(xp, cb, k, xn, es[k]);
                if (s < bs) { bs = s; bk = k; }
            }
        } else {
#pragma unroll 1
            for (int j = 0; j < c; ++j) {
                const int k = slots[tid * 8 + j];
                const float s = exact_sc(xp, cb, k, xn, es[k]);
                if (s < bs || (s == bs && k < bk)) { bs = s; bk = k; }
            }
        }
        bks[tid] = bk;
        out_idx[brow0 + tid] = (float)bk;
    }
    __syncthreads();

    // ---- phase D: coalesced gather-write of x_quantized ----
    float4* oq = reinterpret_cast<float4*>(out_q + brow0 * D_DIM);
#pragma unroll
    for (int j = 0; j < BM * 16 / TPB; ++j) {       // 8
        const int f = tid + TPB * j;     // 0..2047
        const int r = f >> 4, c = f & 15;
        oq[f] = cb4[(size_t)bks[r] * 16 + c];
    }
}

extern "C" void kernel_launch(void* const* d_in, const int* in_sizes, int n_in,
                              void* d_out, int out_size, void* d_ws, size_t ws_size,
                              hipStream_t stream) {
    const float* x  = (const float*)d_in[0];
    const float* cb = (const float*)d_in[1];
    const int n_rows = in_sizes[0] / D_DIM;     // 262144

    float* out_q   = (float*)d_out;
    float* out_idx = out_q + (size_t)n_rows * D_DIM;

    vq_kernel<<<n_rows / BM, TPB, 0, stream>>>(x, cb, out_q, out_idx);
}